// Round 1
// baseline (183.137 us; speedup 1.0000x reference)
//
#include <hip/hip_runtime.h>

#define B_ 16
#define T_ 2048
#define D_ 512
#define A_ 64

typedef __bf16 bf16x8 __attribute__((ext_vector_type(8)));
typedef float  f32x4  __attribute__((ext_vector_type(4)));

__device__ inline unsigned short f2bf(float f){
    union { float f; unsigned u; } x; x.f = f;
    unsigned r = x.u + 0x7fffu + ((x.u >> 16) & 1u);   // RNE
    return (unsigned short)(r >> 16);
}

__device__ inline bf16x8 ldfrag(const unsigned short* p){
    uint4 v = *reinterpret_cast<const uint4*>(p);
    return __builtin_bit_cast(bf16x8, v);
}

// ---------------- W0: build WcT bf16 [192][512] = [Wq|Wk|Wv]^T, zero out ----------------
__global__ void setup_kernel(const float* __restrict__ Wq, const float* __restrict__ Wk,
                             const float* __restrict__ Wv, unsigned short* __restrict__ WcT,
                             float* __restrict__ out){
    int e = blockIdx.x * 256 + threadIdx.x;    // 0..98303
    int j = e >> 9;                            // 0..191
    int d = e & 511;
    float v;
    if (j < 64)       v = Wq[d * 64 + j];
    else if (j < 128) v = Wk[d * 64 + (j - 64)];
    else              v = Wv[d * 64 + (j - 128)];
    WcT[j * 512 + d] = f2bf(v);
    if (e < B_ * D_) out[e] = 0.f;
}

// ---------------- K2: projection GEMM (BT x 512) @ (512 x 192) -> Qb,Kb bf16 + w,kf ------
__global__ __launch_bounds__(256) void proj_kernel(
    const float* __restrict__ inp, const unsigned short* __restrict__ WcT,
    const float* __restrict__ bq, const float* __restrict__ bk, const float* __restrict__ bv,
    unsigned short* __restrict__ Qb, unsigned short* __restrict__ Kb,
    float* __restrict__ wv, float* __restrict__ kf)
{
    __shared__ __align__(16) unsigned short As[128 * 40];   // 128 rows x 32k (pad->40)
    __shared__ __align__(16) unsigned short Bs[192 * 40];   // 192 n   x 32k (pad->40)
    const int tid  = threadIdx.x;
    const int r0   = blockIdx.x * 128;
    const int lane = tid & 63, wvid = tid >> 6;
    const int m = lane & 15, q = lane >> 4;

    f32x4 acc[12][2];
    #pragma unroll
    for (int t = 0; t < 12; t++){
        acc[t][0] = (f32x4){0.f,0.f,0.f,0.f};
        acc[t][1] = (f32x4){0.f,0.f,0.f,0.f};
    }

    for (int kk = 0; kk < 512; kk += 32){
        // stage A: 128x32 fp32 -> bf16
        #pragma unroll
        for (int i = 0; i < 4; i++){
            int row = i * 32 + (tid >> 3);
            int col = (tid & 7) * 4;
            float4 v = *reinterpret_cast<const float4*>(&inp[(size_t)(r0 + row) * 512 + kk + col]);
            ushort4 h; h.x = f2bf(v.x); h.y = f2bf(v.y); h.z = f2bf(v.z); h.w = f2bf(v.w);
            *reinterpret_cast<ushort4*>(&As[row * 40 + col]) = h;
        }
        // stage B: 192x32 bf16 (already n-major, k contiguous)
        #pragma unroll
        for (int it = 0; it < 3; it++){
            int sidx = it * 256 + tid;
            int row = sidx >> 2, seg = sidx & 3;
            uint4 v = *reinterpret_cast<const uint4*>(&WcT[row * 512 + kk + seg * 8]);
            *reinterpret_cast<uint4*>(&Bs[row * 40 + seg * 8]) = v;
        }
        __syncthreads();
        bf16x8 a0 = ldfrag(&As[(32 * wvid + m)      * 40 + q * 8]);
        bf16x8 a1 = ldfrag(&As[(32 * wvid + 16 + m) * 40 + q * 8]);
        #pragma unroll
        for (int t = 0; t < 12; t++){
            bf16x8 bfr = ldfrag(&Bs[(t * 16 + m) * 40 + q * 8]);
            acc[t][0] = __builtin_amdgcn_mfma_f32_16x16x32_bf16(a0, bfr, acc[t][0], 0, 0, 0);
            acc[t][1] = __builtin_amdgcn_mfma_f32_16x16x32_bf16(a1, bfr, acc[t][1], 0, 0, 0);
        }
        __syncthreads();
    }

    // epilogue: bias add, bf16 store, row-sums for masks / vsum
    float bqv[4], bkv[4], bvv[4];
    #pragma unroll
    for (int t = 0; t < 4; t++){
        bqv[t] = bq[t * 16 + m]; bkv[t] = bk[t * 16 + m]; bvv[t] = bv[t * 16 + m];
    }
    #pragma unroll
    for (int f = 0; f < 2; f++){
        float qs[4], ks[4], vs[4];
        #pragma unroll
        for (int i = 0; i < 4; i++){
            size_t r = (size_t)r0 + 32 * wvid + 16 * f + q * 4 + i;
            float sq = 0.f, sk = 0.f, sv = 0.f;
            #pragma unroll
            for (int t = 0; t < 4; t++){
                float vq = acc[t][f][i]     + bqv[t];
                float vk = acc[t + 4][f][i] + bkv[t];
                float vvv = acc[t + 8][f][i] + bvv[t];
                Qb[r * 64 + t * 16 + m] = f2bf(vq);
                Kb[r * 64 + t * 16 + m] = f2bf(vk);
                sq += vq; sk += vk; sv += vvv;
            }
            qs[i] = sq; ks[i] = sk; vs[i] = sv;
        }
        #pragma unroll
        for (int s = 1; s < 16; s <<= 1){
            #pragma unroll
            for (int i = 0; i < 4; i++){
                qs[i] += __shfl_xor(qs[i], s);
                ks[i] += __shfl_xor(ks[i], s);
                vs[i] += __shfl_xor(vs[i], s);
            }
        }
        if (m == 0){
            #pragma unroll
            for (int i = 0; i < 4; i++){
                size_t r = (size_t)r0 + 32 * wvid + 16 * f + q * 4 + i;
                float qmask = (qs[i] == 0.f) ? 0.f : 1.f;
                wv[r] = qmask * vs[i];                 // q_mask * vsum
                kf[r] = (ks[i] == 0.f) ? 1.f : 0.f;    // 1 => masked key
            }
        }
    }
}

// ---------------- K3: flash-style reduce: c[b,t] = sum_s softmax * w[s] ------------------
__global__ __launch_bounds__(256) void attn_kernel(
    const unsigned short* __restrict__ Qb, const unsigned short* __restrict__ Kb,
    const float* __restrict__ wv, const float* __restrict__ kf, float* __restrict__ c)
{
    __shared__ __align__(16) unsigned short Qs[64 * 72];
    __shared__ __align__(16) unsigned short Ks[64 * 72];
    __shared__ float wsh[64];
    __shared__ float kfs[64];
    const int tid = threadIdx.x;
    const int b   = blockIdx.y;
    const int t0  = blockIdx.x * 64;
    const int lane = tid & 63, wvid = tid >> 6;
    const int m = lane & 15, q = lane >> 4;
    const size_t base = (size_t)b * T_;

    {   // stage Q tile once
        int row = tid >> 2, seg = tid & 3;
        const uint4* src = reinterpret_cast<const uint4*>(&Qb[(base + t0 + row) * 64 + seg * 16]);
        uint4* dst = reinterpret_cast<uint4*>(&Qs[row * 72 + seg * 16]);
        dst[0] = src[0]; dst[1] = src[1];
    }

    float mrun[4], num[4], den[4];
    #pragma unroll
    for (int i = 0; i < 4; i++){ mrun[i] = -1e30f; num[i] = 0.f; den[i] = 0.f; }

    for (int s0 = 0; s0 < T_; s0 += 64){
        __syncthreads();
        {
            int row = tid >> 2, seg = tid & 3;
            const uint4* src = reinterpret_cast<const uint4*>(&Kb[(base + s0 + row) * 64 + seg * 16]);
            uint4* dst = reinterpret_cast<uint4*>(&Ks[row * 72 + seg * 16]);
            dst[0] = src[0]; dst[1] = src[1];
            if (tid < 64)       wsh[tid]      = wv[base + s0 + tid];
            else if (tid < 128) kfs[tid - 64] = kf[base + s0 + tid - 64];
        }
        __syncthreads();
        bf16x8 a0 = ldfrag(&Qs[(16 * wvid + m) * 72 + q * 8]);
        bf16x8 a1 = ldfrag(&Qs[(16 * wvid + m) * 72 + 32 + q * 8]);
        f32x4 sacc[4];
        #pragma unroll
        for (int st = 0; st < 4; st++){
            bf16x8 b0 = ldfrag(&Ks[(st * 16 + m) * 72 + q * 8]);
            bf16x8 b1 = ldfrag(&Ks[(st * 16 + m) * 72 + 32 + q * 8]);
            f32x4 z = (f32x4){0.f,0.f,0.f,0.f};
            z = __builtin_amdgcn_mfma_f32_16x16x32_bf16(a0, b0, z, 0, 0, 0);
            z = __builtin_amdgcn_mfma_f32_16x16x32_bf16(a1, b1, z, 0, 0, 0);
            sacc[st] = z;
        }
        float wcol[4], kcol[4];
        #pragma unroll
        for (int st = 0; st < 4; st++){ wcol[st] = wsh[st * 16 + m]; kcol[st] = kfs[st * 16 + m]; }
        float sc[4][4];
        #pragma unroll
        for (int st = 0; st < 4; st++)
            #pragma unroll
            for (int i = 0; i < 4; i++)
                sc[st][i] = (kcol[st] != 0.f) ? 1e-8f : sacc[st][i] * 0.125f;
        #pragma unroll
        for (int i = 0; i < 4; i++){
            float rm = fmaxf(fmaxf(sc[0][i], sc[1][i]), fmaxf(sc[2][i], sc[3][i]));
            #pragma unroll
            for (int s = 1; s < 16; s <<= 1) rm = fmaxf(rm, __shfl_xor(rm, s));
            float nm  = fmaxf(mrun[i], rm);
            float fac = __expf(mrun[i] - nm);
            num[i] *= fac; den[i] *= fac; mrun[i] = nm;
            #pragma unroll
            for (int st = 0; st < 4; st++){
                float e = __expf(sc[st][i] - nm);
                den[i] += e; num[i] += e * wcol[st];
            }
        }
    }
    #pragma unroll
    for (int s = 1; s < 16; s <<= 1){
        #pragma unroll
        for (int i = 0; i < 4; i++){ num[i] += __shfl_xor(num[i], s); den[i] += __shfl_xor(den[i], s); }
    }
    if (m == 0){
        #pragma unroll
        for (int i = 0; i < 4; i++)
            c[base + t0 + 16 * wvid + q * 4 + i] = num[i] / den[i];
    }
}

// ---------------- K4: out[b,d] = sum_t inp[b,t,d] * c[b,t] ------------------------------
__global__ __launch_bounds__(256) void out_kernel(
    const float* __restrict__ inp, const float* __restrict__ c, float* __restrict__ out)
{
    const int tid = threadIdx.x;
    const int b   = blockIdx.y;
    const int t0  = blockIdx.x * 64;
    const size_t base = (size_t)b * T_;
    float a0 = 0.f, a1 = 0.f;
    for (int t = 0; t < 64; t++){
        float ct = c[base + t0 + t];
        const float* row = inp + (base + t0 + t) * 512;
        a0 += row[tid] * ct;
        a1 += row[tid + 256] * ct;
    }
    atomicAdd(&out[b * 512 + tid], a0);
    atomicAdd(&out[b * 512 + tid + 256], a1);
}

extern "C" void kernel_launch(void* const* d_in, const int* in_sizes, int n_in,
                              void* d_out, int out_size, void* d_ws, size_t ws_size,
                              hipStream_t stream)
{
    const float* inp = (const float*)d_in[0];
    const float* Wq  = (const float*)d_in[1];
    const float* bq  = (const float*)d_in[2];
    const float* Wk  = (const float*)d_in[3];
    const float* bk  = (const float*)d_in[4];
    const float* Wv  = (const float*)d_in[5];
    const float* bv  = (const float*)d_in[6];
    float* out = (float*)d_out;

    char* ws = (char*)d_ws;
    unsigned short* WcT = (unsigned short*)(ws);                         // 196608 B
    unsigned short* Qb  = (unsigned short*)(ws + 262144);                // 4 MiB
    unsigned short* Kb  = (unsigned short*)(ws + 262144 + 4194304);      // 4 MiB
    float* wvp = (float*)(ws + 262144 + 2 * 4194304);                    // 128 KiB
    float* kfp = (float*)(ws + 262144 + 2 * 4194304 + 131072);           // 128 KiB
    float* cc  = (float*)(ws + 262144 + 2 * 4194304 + 2 * 131072);       // 128 KiB

    setup_kernel<<<384, 256, 0, stream>>>(Wq, Wk, Wv, WcT, out);
    proj_kernel<<<256, 256, 0, stream>>>(inp, WcT, bq, bk, bv, Qb, Kb, wvp, kfp);
    attn_kernel<<<dim3(32, 16), 256, 0, stream>>>(Qb, Kb, wvp, kfp, cc);
    out_kernel<<<dim3(32, 16), 256, 0, stream>>>(inp, cc, out);
}